// Round 1
// baseline (7907.380 us; speedup 1.0000x reference)
//
#include <hip/hip_runtime.h>

typedef unsigned short u16;
using f32x4 = __attribute__((ext_vector_type(4))) float;
using s16x8 = __attribute__((ext_vector_type(8))) short;

constexpr int Tn = 512, Bn = 64, Hn = 512, Gn = 2048, On = 128;

// -------- workspace layout (bytes) --------
constexpr size_t OFF_BAR  = 0;                                  // 1024 B (2 counters)
constexpr size_t OFF_HBUF = 1024;                               // [2][B][H] bf16 = 128 KB
constexpr size_t OFF_CMID = OFF_HBUF + 2ull * Bn * Hn * 2;      // [B][H] f32 = 128 KB
constexpr size_t OFF_Y1   = OFF_CMID + (size_t)Bn * Hn * 4;     // [T][B][H] bf16 = 32 MB
constexpr size_t OFF_XG   = OFF_Y1 + (size_t)Tn * Bn * Hn * 2;  // [T][G][B] bf16 = 128 MB

// -------- helpers --------
__device__ __forceinline__ u16 f2b(float f) {
  union { float f; unsigned u; } v; v.f = f;
  unsigned r = v.u + 0x7fffu + ((v.u >> 16) & 1u);
  return (u16)(r >> 16);
}
__device__ __forceinline__ float b2f(u16 u) {
  union { unsigned u; float f; } v; v.u = ((unsigned)u) << 16; return v.f;
}
__device__ __forceinline__ s16x8 pack8(float4 lo, float4 hi) {
  s16x8 r;
  r[0] = (short)f2b(lo.x); r[1] = (short)f2b(lo.y); r[2] = (short)f2b(lo.z); r[3] = (short)f2b(lo.w);
  r[4] = (short)f2b(hi.x); r[5] = (short)f2b(hi.y); r[6] = (short)f2b(hi.z); r[7] = (short)f2b(hi.w);
  return r;
}
__device__ __forceinline__ float sigm(float x) {
  float e = __builtin_amdgcn_exp2f(-1.4426950408889634f * x);
  return __builtin_amdgcn_rcpf(1.0f + e);
}
__device__ __forceinline__ float tanh_(float x) {
  float e = __builtin_amdgcn_exp2f(-2.885390081777927f * x);
  return __builtin_amdgcn_rcpf(1.0f + e) * 2.0f - 1.0f;
}

// monotonic-counter grid barrier (counter zeroed by host memset each launch)
__device__ __forceinline__ void grid_barrier(unsigned* cnt, unsigned target) {
  __syncthreads();
  if (threadIdx.x == 0) {
    __hip_atomic_fetch_add(cnt, 1u, __ATOMIC_RELEASE, __HIP_MEMORY_SCOPE_AGENT);
    while (__hip_atomic_load(cnt, __ATOMIC_ACQUIRE, __HIP_MEMORY_SCOPE_AGENT) < target) {
      __builtin_amdgcn_s_sleep(1);
    }
  }
  __syncthreads();
}

// -------- projection GEMM: xg[t][n][b] = A[m][:] . W[n][:] + bih[n] + bhh[n] --------
// A: [32768][512] (f32 or bf16), W: [2048][512] f32 (B^T layout). Tile 128x128 per WG.
template<bool AF32>
__global__ __launch_bounds__(256)
void proj_kernel(const void* __restrict__ Ap, const float* __restrict__ W,
                 const float* __restrict__ bih, const float* __restrict__ bhh,
                 u16* __restrict__ xg)
{
  const int lane = threadIdx.x & 63, wave = threadIdx.x >> 6;
  const int lrow = lane & 15, lk8 = (lane >> 4) << 3;
  const int m0 = blockIdx.x * 128 + (wave & 1) * 64;
  const int n0 = blockIdx.y * 128 + (wave >> 1) * 64;
  f32x4 acc[4][4] = {};
  for (int ks = 0; ks < 16; ++ks) {
    const int k0 = ks * 32 + lk8;
    s16x8 af[4], bfr[4];
#pragma unroll
    for (int mt = 0; mt < 4; ++mt) {
      const int row = m0 + mt * 16 + lrow;
      if constexpr (AF32) {
        const float* ap = (const float*)Ap + (size_t)row * Hn + k0;
        float4 lo = *(const float4*)ap, hi = *(const float4*)(ap + 4);
        af[mt] = pack8(lo, hi);
      } else {
        af[mt] = *(const s16x8*)((const u16*)Ap + (size_t)row * Hn + k0);
      }
    }
#pragma unroll
    for (int nt = 0; nt < 4; ++nt) {
      const float* wp = W + (size_t)(n0 + nt * 16 + lrow) * Hn + k0;
      float4 lo = *(const float4*)wp, hi = *(const float4*)(wp + 4);
      bfr[nt] = pack8(lo, hi);
    }
#pragma unroll
    for (int mt = 0; mt < 4; ++mt)
#pragma unroll
      for (int nt = 0; nt < 4; ++nt)
        acc[mt][nt] = __builtin_amdgcn_mfma_f32_16x16x32_bf16(af[mt], bfr[nt], acc[mt][nt], 0, 0, 0);
  }
  const int rbase = (lane >> 4) << 2;
#pragma unroll
  for (int nt = 0; nt < 4; ++nt) {
    const int n = n0 + nt * 16 + lrow;
    const float bias = bih[n] + bhh[n];
#pragma unroll
    for (int mt = 0; mt < 4; ++mt) {
      const int m = m0 + mt * 16 + rbase;
      const int t = m >> 6, b = m & 63;
      ushort4 v;
      v.x = f2b(acc[mt][nt][0] + bias);
      v.y = f2b(acc[mt][nt][1] + bias);
      v.z = f2b(acc[mt][nt][2] + bias);
      v.w = f2b(acc[mt][nt][3] + bias);
      *(ushort4*)(xg + ((size_t)t * Gn + n) * Bn + b) = v;
    }
  }
}

// -------- persistent LSTM scan --------
// 64 WGs x 256 thr. WG owns 8 h-columns (j0..j0+7) -> 32 W_hh rows, weights in registers.
// Thread (wave,lane): b = wave*16 + (lane>>4)*4 + r (r=0..3), j = j0 + (lane&7).
__global__ __launch_bounds__(256)
void scan_kernel(const u16* __restrict__ xg, const float* __restrict__ Whh,
                 const float* __restrict__ hinit, const float* __restrict__ cinit,
                 u16* __restrict__ hbuf, u16* __restrict__ y1,
                 float* __restrict__ c_fin, float* __restrict__ h_fin,
                 unsigned* __restrict__ bar, const int phase)
{
  const int wg = blockIdx.x;
  const int lane = threadIdx.x & 63, wave = threadIdx.x >> 6;
  const int x16 = lane & 15, grp = lane >> 4, lk8 = grp << 3;
  const int j0 = wg * 8, jj = x16 & 7;
  const int bbase = wave * 16 + (grp << 2);

  // preload weight fragments into registers: bw[ntile][kstep]
  s16x8 bw[2][16];
#pragma unroll
  for (int nt = 0; nt < 2; ++nt) {
    const int n = nt * 16 + x16;
    const int grow = (n >> 3) * Hn + j0 + (n & 7);
#pragma unroll
    for (int ks = 0; ks < 16; ++ks) {
      const float* wp = Whh + (size_t)grow * Hn + ks * 32 + lk8;
      float4 lo = *(const float4*)wp, hi = *(const float4*)(wp + 4);
      bw[nt][ks] = pack8(lo, hi);
    }
  }
  float c[4];
#pragma unroll
  for (int r = 0; r < 4; ++r) c[r] = cinit[(size_t)(bbase + r) * Hn + j0 + jj];

  if (phase == 1) {  // init rolling h buffer [parity 0] from h0
    for (int k = threadIdx.x; k < Hn; k += 256)
      hbuf[(size_t)wg * Hn + k] = f2b(hinit[(size_t)wg * Hn + k]);
  }
  unsigned epoch = 1;
  grid_barrier(bar, epoch * 64);

  for (int t = 0; t < Tn; ++t) {
    const u16* hprev = hbuf + (size_t)(t & 1) * Bn * Hn;
    // acc init = xg slice (already in C-fragment layout)
    f32x4 acc[2];
#pragma unroll
    for (int nt = 0; nt < 2; ++nt) {
      const int n = nt * 16 + x16;
      const int grow = (n >> 3) * Hn + j0 + (n & 7);
      ushort4 v = *(const ushort4*)(xg + ((size_t)t * Gn + grow) * Bn + bbase);
      acc[nt][0] = b2f(v.x); acc[nt][1] = b2f(v.y);
      acc[nt][2] = b2f(v.z); acc[nt][3] = b2f(v.w);
    }
    const u16* arow = hprev + (size_t)(wave * 16 + x16) * Hn + lk8;
#pragma unroll
    for (int ks = 0; ks < 16; ++ks) {
      s16x8 a = *(const s16x8*)(arow + ks * 32);
      acc[0] = __builtin_amdgcn_mfma_f32_16x16x32_bf16(a, bw[0][ks], acc[0], 0, 0, 0);
      acc[1] = __builtin_amdgcn_mfma_f32_16x16x32_bf16(a, bw[1][ks], acc[1], 0, 0, 0);
    }
    // tile0 rows: i(j) / f(j); tile1 rows: g(j) / o(j); pair via shfl_xor(8)
    u16* hnext = hbuf + (size_t)((t + 1) & 1) * Bn * Hn;
    float hv[4];
#pragma unroll
    for (int r = 0; r < 4; ++r) {
      const float p0 = acc[0][r], p1 = acc[1][r];
      const float q0 = __shfl_xor(p0, 8, 64);
      const float q1 = __shfl_xor(p1, 8, 64);
      const bool lo = (x16 < 8);
      const float gi = lo ? p0 : q0;
      const float gf = lo ? q0 : p0;
      const float gg = lo ? p1 : q1;
      const float go = lo ? q1 : p1;
      const float cn = sigm(gf) * c[r] + sigm(gi) * tanh_(gg);
      c[r] = cn;
      hv[r] = sigm(go) * tanh_(cn);
    }
    if (x16 < 8) {
#pragma unroll
      for (int r = 0; r < 4; ++r) {
        const int b = bbase + r;
        const u16 hb = f2b(hv[r]);
        hnext[(size_t)b * Hn + j0 + jj] = hb;
        if (phase == 1) y1[((size_t)t * Bn + b) * Hn + j0 + jj] = hb;
        if (phase == 2 && t == Tn - 1) {
          h_fin[(size_t)b * Hn + j0 + jj] = hv[r];
          c_fin[(size_t)b * Hn + j0 + jj] = c[r];
        }
      }
    }
    ++epoch;
    grid_barrier(bar, epoch * 64);
  }
  if (phase == 1 && x16 < 8) {
#pragma unroll
    for (int r = 0; r < 4; ++r) c_fin[(size_t)(bbase + r) * Hn + j0 + jj] = c[r];
  }
}

// -------- output head: out[b][o] = h2[b][:] . Wout[o][:] + bout[o] --------
__global__ __launch_bounds__(128)
void out_kernel(const float* __restrict__ h2, const float* __restrict__ Wout,
                const float* __restrict__ bout, float* __restrict__ out)
{
  const int b = blockIdx.x, o = threadIdx.x;
  const float4* hp = (const float4*)(h2 + (size_t)b * Hn);
  const float4* wp = (const float4*)(Wout + (size_t)o * Hn);
  float acc = 0.f;
#pragma unroll 4
  for (int k = 0; k < Hn / 4; ++k) {
    float4 h4 = hp[k], w4 = wp[k];
    acc += h4.x * w4.x + h4.y * w4.y + h4.z * w4.z + h4.w * w4.w;
  }
  out[(size_t)b * On + o] = acc + bout[o];
}

extern "C" void kernel_launch(void* const* d_in, const int* in_sizes, int n_in,
                              void* d_out, int out_size, void* d_ws, size_t ws_size,
                              hipStream_t stream) {
  const float* x     = (const float*)d_in[0];
  const float* h0    = (const float*)d_in[1];
  const float* c0    = (const float*)d_in[2];
  const float* W_ih1 = (const float*)d_in[3];
  const float* W_hh1 = (const float*)d_in[4];
  const float* b_ih1 = (const float*)d_in[5];
  const float* b_hh1 = (const float*)d_in[6];
  const float* W_ih2 = (const float*)d_in[7];
  const float* W_hh2 = (const float*)d_in[8];
  const float* b_ih2 = (const float*)d_in[9];
  const float* b_hh2 = (const float*)d_in[10];
  const float* W_out = (const float*)d_in[11];
  const float* b_out = (const float*)d_in[12];

  float* out    = (float*)d_out;
  float* h2_out = out + (size_t)Bn * On;                    // 8192
  float* c2_out = h2_out + (size_t)Bn * Hn;                 // 8192 + 32768

  char* w = (char*)d_ws;
  unsigned* bar1 = (unsigned*)(w + OFF_BAR);
  unsigned* bar2 = bar1 + 64;
  u16*   hbuf  = (u16*)(w + OFF_HBUF);
  float* c_mid = (float*)(w + OFF_CMID);
  u16*   y1    = (u16*)(w + OFF_Y1);
  u16*   xg    = (u16*)(w + OFF_XG);

  hipMemsetAsync(w, 0, 1024, stream);  // zero barrier counters (replay-safe)

  dim3 pgrid(256, 16);
  proj_kernel<true ><<<pgrid, 256, 0, stream>>>(x,  W_ih1, b_ih1, b_hh1, xg);
  scan_kernel<<<64, 256, 0, stream>>>(xg, W_hh1, h0, c0, hbuf, y1, c_mid, nullptr, bar1, 1);
  proj_kernel<false><<<pgrid, 256, 0, stream>>>(y1, W_ih2, b_ih2, b_hh2, xg);
  scan_kernel<<<64, 256, 0, stream>>>(xg, W_hh2, nullptr, c_mid, hbuf, y1, c2_out, h2_out, bar2, 2);
  out_kernel<<<64, 128, 0, stream>>>(h2_out, W_out, b_out, out);
}

// Round 2
// 7402.931 us; speedup vs baseline: 1.0681x; 1.0681x over previous
//
#include <hip/hip_runtime.h>

typedef unsigned short u16;
typedef unsigned long long u64;
using f32x4 = __attribute__((ext_vector_type(4))) float;
using s16x8 = __attribute__((ext_vector_type(8))) short;

constexpr int Tn = 512, Bn = 64, Hn = 512, Gn = 2048, On = 128;

// -------- workspace layout (bytes) --------
constexpr size_t OFF_BAR  = 0;                                  // 1024 B (2 counters)
constexpr size_t OFF_HBUF = 1024;                               // [2][B][H] bf16 = 128 KB
constexpr size_t OFF_CMID = OFF_HBUF + 2ull * Bn * Hn * 2;      // [B][H] f32 = 128 KB
constexpr size_t OFF_Y1   = OFF_CMID + (size_t)Bn * Hn * 4;     // [T][B][H] bf16 = 32 MB
constexpr size_t OFF_XG   = OFF_Y1 + (size_t)Tn * Bn * Hn * 2;  // [T][G][B] bf16 = 128 MB

// -------- helpers --------
__device__ __forceinline__ u16 f2b(float f) {
  union { float f; unsigned u; } v; v.f = f;
  unsigned r = v.u + 0x7fffu + ((v.u >> 16) & 1u);
  return (u16)(r >> 16);
}
__device__ __forceinline__ float b2f(u16 u) {
  union { unsigned u; float f; } v; v.u = ((unsigned)u) << 16; return v.f;
}
__device__ __forceinline__ s16x8 pack8(float4 lo, float4 hi) {
  s16x8 r;
  r[0] = (short)f2b(lo.x); r[1] = (short)f2b(lo.y); r[2] = (short)f2b(lo.z); r[3] = (short)f2b(lo.w);
  r[4] = (short)f2b(hi.x); r[5] = (short)f2b(hi.y); r[6] = (short)f2b(hi.z); r[7] = (short)f2b(hi.w);
  return r;
}
__device__ __forceinline__ float sigm(float x) {
  float e = __builtin_amdgcn_exp2f(-1.4426950408889634f * x);
  return __builtin_amdgcn_rcpf(1.0f + e);
}
__device__ __forceinline__ float tanh_(float x) {
  float e = __builtin_amdgcn_exp2f(-2.885390081777927f * x);
  return __builtin_amdgcn_rcpf(1.0f + e) * 2.0f - 1.0f;
}
// agent-scope (device-coherent, L2-bypassing) relaxed atomics
__device__ __forceinline__ u64 ld64_sc(const u64* p) {
  return __hip_atomic_load(p, __ATOMIC_RELAXED, __HIP_MEMORY_SCOPE_AGENT);
}
__device__ __forceinline__ void st64_sc(u64* p, u64 v) {
  __hip_atomic_store(p, v, __ATOMIC_RELAXED, __HIP_MEMORY_SCOPE_AGENT);
}

// -------- projection GEMM: xg[t][n][b] = A[m][:] . W[n][:] + bih[n] + bhh[n] --------
template<bool AF32>
__global__ __launch_bounds__(256)
void proj_kernel(const void* __restrict__ Ap, const float* __restrict__ W,
                 const float* __restrict__ bih, const float* __restrict__ bhh,
                 u16* __restrict__ xg)
{
  const int lane = threadIdx.x & 63, wave = threadIdx.x >> 6;
  const int lrow = lane & 15, lk8 = (lane >> 4) << 3;
  const int m0 = blockIdx.x * 128 + (wave & 1) * 64;
  const int n0 = blockIdx.y * 128 + (wave >> 1) * 64;
  f32x4 acc[4][4] = {};
  for (int ks = 0; ks < 16; ++ks) {
    const int k0 = ks * 32 + lk8;
    s16x8 af[4], bfr[4];
#pragma unroll
    for (int mt = 0; mt < 4; ++mt) {
      const int row = m0 + mt * 16 + lrow;
      if constexpr (AF32) {
        const float* ap = (const float*)Ap + (size_t)row * Hn + k0;
        float4 lo = *(const float4*)ap, hi = *(const float4*)(ap + 4);
        af[mt] = pack8(lo, hi);
      } else {
        af[mt] = *(const s16x8*)((const u16*)Ap + (size_t)row * Hn + k0);
      }
    }
#pragma unroll
    for (int nt = 0; nt < 4; ++nt) {
      const float* wp = W + (size_t)(n0 + nt * 16 + lrow) * Hn + k0;
      float4 lo = *(const float4*)wp, hi = *(const float4*)(wp + 4);
      bfr[nt] = pack8(lo, hi);
    }
#pragma unroll
    for (int mt = 0; mt < 4; ++mt)
#pragma unroll
      for (int nt = 0; nt < 4; ++nt)
        acc[mt][nt] = __builtin_amdgcn_mfma_f32_16x16x32_bf16(af[mt], bfr[nt], acc[mt][nt], 0, 0, 0);
  }
  const int rbase = (lane >> 4) << 2;
#pragma unroll
  for (int nt = 0; nt < 4; ++nt) {
    const int n = n0 + nt * 16 + lrow;
    const float bias = bih[n] + bhh[n];
#pragma unroll
    for (int mt = 0; mt < 4; ++mt) {
      const int m = m0 + mt * 16 + rbase;
      const int t = m >> 6, b = m & 63;
      ushort4 v;
      v.x = f2b(acc[mt][nt][0] + bias);
      v.y = f2b(acc[mt][nt][1] + bias);
      v.z = f2b(acc[mt][nt][2] + bias);
      v.w = f2b(acc[mt][nt][3] + bias);
      *(ushort4*)(xg + ((size_t)t * Gn + n) * Bn + b) = v;
    }
  }
}

// -------- persistent LSTM scan (fence-free flag-exchange barrier) --------
// 64 WGs x 256 thr. WG owns 8 h-columns (j0..j0+7) -> 32 W_hh rows in registers.
__global__ __launch_bounds__(256, 1)
void scan_kernel(const u16* __restrict__ xg, const float* __restrict__ Whh,
                 const float* __restrict__ hinit, const float* __restrict__ cinit,
                 u16* __restrict__ hbuf, u16* __restrict__ y1,
                 float* __restrict__ c_fin, float* __restrict__ h_fin,
                 unsigned* __restrict__ bar, const int phase)
{
  const int wg = blockIdx.x;
  const int lane = threadIdx.x & 63, wave = threadIdx.x >> 6;
  const int x16 = lane & 15, grp = lane >> 4, lk8 = grp << 3;
  const int j0 = wg * 8, jj = x16 & 7;
  const int bbase = wave * 16 + (grp << 2);

  __shared__ u16 hstage[Bn][8];

  // preload weight fragments into registers: bw[ntile][kstep]
  s16x8 bw[2][16];
#pragma unroll
  for (int nt = 0; nt < 2; ++nt) {
    const int n = nt * 16 + x16;
    const int grow = (n >> 3) * Hn + j0 + (n & 7);
#pragma unroll
    for (int ks = 0; ks < 16; ++ks) {
      const float* wp = Whh + (size_t)grow * Hn + ks * 32 + lk8;
      float4 lo = *(const float4*)wp, hi = *(const float4*)(wp + 4);
      bw[nt][ks] = pack8(lo, hi);
    }
  }
  float c[4];
#pragma unroll
  for (int r = 0; r < 4; ++r) c[r] = cinit[(size_t)(bbase + r) * Hn + j0 + jj];

  if (phase == 1) {  // init rolling h buffer [parity 0] from h0, write-through
    if (threadIdx.x < 128) {
      const int kk = threadIdx.x * 4;
      const float* hp = hinit + (size_t)wg * Hn + kk;
      u64 v = (u64)f2b(hp[0]) | ((u64)f2b(hp[1]) << 16)
            | ((u64)f2b(hp[2]) << 32) | ((u64)f2b(hp[3]) << 48);
      st64_sc((u64*)(hbuf + (size_t)wg * Hn + kk), v);
    }
  }
  unsigned epoch = 1;
  asm volatile("s_waitcnt vmcnt(0)" ::: "memory");
  __syncthreads();
  if (threadIdx.x == 0) {
    __hip_atomic_fetch_add(bar, 1u, __ATOMIC_RELAXED, __HIP_MEMORY_SCOPE_AGENT);
    while (__hip_atomic_load(bar, __ATOMIC_RELAXED, __HIP_MEMORY_SCOPE_AGENT) < 64u * epoch)
      __builtin_amdgcn_s_sleep(2);
  }
  __syncthreads();

  // xg fragment addresses (C-layout) + prefetch t=0
  int grow0, grow1;
  { int n = x16;      grow0 = (n >> 3) * Hn + j0 + (n & 7); }
  { int n = 16 + x16; grow1 = (n >> 3) * Hn + j0 + (n & 7); }
  ushort4 xv0 = *(const ushort4*)(xg + ((size_t)0 * Gn + grow0) * Bn + bbase);
  ushort4 xv1 = *(const ushort4*)(xg + ((size_t)0 * Gn + grow1) * Bn + bbase);

  for (int t = 0; t < Tn; ++t) {
    const u16* hprev = hbuf + (size_t)(t & 1) * Bn * Hn;
    u16* hnext = hbuf + (size_t)((t + 1) & 1) * Bn * Hn;

    // issue device-coherent h loads (bypass stale L1/L2)
    const u64* arow = (const u64*)(hprev + (size_t)(wave * 16 + x16) * Hn + lk8);
    s16x8 afr[16];
#pragma unroll
    for (int ks = 0; ks < 16; ++ks) {
      union { u64 q[2]; s16x8 v; } u;
      u.q[0] = ld64_sc(arow + ks * 8);
      u.q[1] = ld64_sc(arow + ks * 8 + 1);
      afr[ks] = u.v;
    }
    // prefetch next step's xg slice (plain cached loads, off critical path)
    ushort4 xn0, xn1;
    if (t + 1 < Tn) {
      xn0 = *(const ushort4*)(xg + ((size_t)(t + 1) * Gn + grow0) * Bn + bbase);
      xn1 = *(const ushort4*)(xg + ((size_t)(t + 1) * Gn + grow1) * Bn + bbase);
    }

    f32x4 acc[2];
    acc[0][0] = b2f(xv0.x); acc[0][1] = b2f(xv0.y); acc[0][2] = b2f(xv0.z); acc[0][3] = b2f(xv0.w);
    acc[1][0] = b2f(xv1.x); acc[1][1] = b2f(xv1.y); acc[1][2] = b2f(xv1.z); acc[1][3] = b2f(xv1.w);
#pragma unroll
    for (int ks = 0; ks < 16; ++ks) {
      acc[0] = __builtin_amdgcn_mfma_f32_16x16x32_bf16(afr[ks], bw[0][ks], acc[0], 0, 0, 0);
      acc[1] = __builtin_amdgcn_mfma_f32_16x16x32_bf16(afr[ks], bw[1][ks], acc[1], 0, 0, 0);
    }
    // tile0 rows: i(j) / f(j); tile1 rows: g(j) / o(j); pair via shfl_xor(8)
    float hv[4];
#pragma unroll
    for (int r = 0; r < 4; ++r) {
      const float p0 = acc[0][r], p1 = acc[1][r];
      const float q0 = __shfl_xor(p0, 8, 64);
      const float q1 = __shfl_xor(p1, 8, 64);
      const bool lo = (x16 < 8);
      const float gi = lo ? p0 : q0;
      const float gf = lo ? q0 : p0;
      const float gg = lo ? p1 : q1;
      const float go = lo ? q1 : p1;
      const float cn = sigm(gf) * c[r] + sigm(gi) * tanh_(gg);
      c[r] = cn;
      hv[r] = sigm(go) * tanh_(cn);
    }
    if (x16 < 8) {
#pragma unroll
      for (int r = 0; r < 4; ++r) {
        const int b = bbase + r;
        const u16 hb = f2b(hv[r]);
        hstage[b][jj] = hb;
        if (phase == 1) y1[((size_t)t * Bn + b) * Hn + j0 + jj] = hb;
        if (phase == 2 && t == Tn - 1) {
          h_fin[(size_t)b * Hn + j0 + jj] = hv[r];
          c_fin[(size_t)b * Hn + j0 + jj] = c[r];
        }
      }
    }
    __syncthreads();
    if (threadIdx.x < 128) {  // coalesced write-through publish of this WG's h slice
      const int b = threadIdx.x >> 1, q = threadIdx.x & 1;
      const u64 v = *(const u64*)&hstage[b][q * 4];
      st64_sc((u64*)(hnext + (size_t)b * Hn + j0) + q, v);
    }
    if (t + 1 < Tn) { xv0 = xn0; xv1 = xn1; }
    ++epoch;
    asm volatile("s_waitcnt vmcnt(0)" ::: "memory");  // h publish ack'd at coherence point
    __syncthreads();                                   // ...by ALL waves of this WG
    if (threadIdx.x == 0) {
      __hip_atomic_fetch_add(bar, 1u, __ATOMIC_RELAXED, __HIP_MEMORY_SCOPE_AGENT);
      while (__hip_atomic_load(bar, __ATOMIC_RELAXED, __HIP_MEMORY_SCOPE_AGENT) < 64u * epoch)
        __builtin_amdgcn_s_sleep(2);
    }
    __syncthreads();
  }
  if (phase == 1 && x16 < 8) {
#pragma unroll
    for (int r = 0; r < 4; ++r) c_fin[(size_t)(bbase + r) * Hn + j0 + jj] = c[r];
  }
}

// -------- output head: out[b][o] = h2[b][:] . Wout[o][:] + bout[o] --------
__global__ __launch_bounds__(128)
void out_kernel(const float* __restrict__ h2, const float* __restrict__ Wout,
                const float* __restrict__ bout, float* __restrict__ out)
{
  const int b = blockIdx.x, o = threadIdx.x;
  const float4* hp = (const float4*)(h2 + (size_t)b * Hn);
  const float4* wp = (const float4*)(Wout + (size_t)o * Hn);
  float acc = 0.f;
#pragma unroll 4
  for (int k = 0; k < Hn / 4; ++k) {
    float4 h4 = hp[k], w4 = wp[k];
    acc += h4.x * w4.x + h4.y * w4.y + h4.z * w4.z + h4.w * w4.w;
  }
  out[(size_t)b * On + o] = acc + bout[o];
}

extern "C" void kernel_launch(void* const* d_in, const int* in_sizes, int n_in,
                              void* d_out, int out_size, void* d_ws, size_t ws_size,
                              hipStream_t stream) {
  const float* x     = (const float*)d_in[0];
  const float* h0    = (const float*)d_in[1];
  const float* c0    = (const float*)d_in[2];
  const float* W_ih1 = (const float*)d_in[3];
  const float* W_hh1 = (const float*)d_in[4];
  const float* b_ih1 = (const float*)d_in[5];
  const float* b_hh1 = (const float*)d_in[6];
  const float* W_ih2 = (const float*)d_in[7];
  const float* W_hh2 = (const float*)d_in[8];
  const float* b_ih2 = (const float*)d_in[9];
  const float* b_hh2 = (const float*)d_in[10];
  const float* W_out = (const float*)d_in[11];
  const float* b_out = (const float*)d_in[12];

  float* out    = (float*)d_out;
  float* h2_out = out + (size_t)Bn * On;
  float* c2_out = h2_out + (size_t)Bn * Hn;

  char* w = (char*)d_ws;
  unsigned* bar1 = (unsigned*)(w + OFF_BAR);
  unsigned* bar2 = bar1 + 64;
  u16*   hbuf  = (u16*)(w + OFF_HBUF);
  float* c_mid = (float*)(w + OFF_CMID);
  u16*   y1    = (u16*)(w + OFF_Y1);
  u16*   xg    = (u16*)(w + OFF_XG);

  hipMemsetAsync(w, 0, 1024, stream);  // zero barrier counters (replay-safe)

  dim3 pgrid(256, 16);
  proj_kernel<true ><<<pgrid, 256, 0, stream>>>(x,  W_ih1, b_ih1, b_hh1, xg);
  scan_kernel<<<64, 256, 0, stream>>>(xg, W_hh1, h0, c0, hbuf, y1, c_mid, nullptr, bar1, 1);
  proj_kernel<false><<<pgrid, 256, 0, stream>>>(y1, W_ih2, b_ih2, b_hh2, xg);
  scan_kernel<<<64, 256, 0, stream>>>(xg, W_hh2, nullptr, c_mid, hbuf, y1, c2_out, h2_out, bar2, 2);
  out_kernel<<<64, 128, 0, stream>>>(h2_out, W_out, b_out, out);
}

// Round 3
// 4356.027 us; speedup vs baseline: 1.8153x; 1.6995x over previous
//
#include <hip/hip_runtime.h>

typedef unsigned short u16;
typedef unsigned int u32;
typedef unsigned long long u64;
using f32x4 = __attribute__((ext_vector_type(4))) float;
using s16x8 = __attribute__((ext_vector_type(8))) short;
using u64x2 = __attribute__((ext_vector_type(2))) unsigned long long;

constexpr int Tn = 512, Bn = 64, Hn = 512, Gn = 2048, On = 128;
constexpr int NS = 16;  // gate-slice WGs per batch group (exchange set)
constexpr int NG = 4;   // batch groups (no cross-group communication)

// -------- workspace layout (bytes) --------
constexpr size_t OFF_BAR  = 0;                                  // 1024 B: scan1 flags [4 grp x 128B], scan2 at +512
constexpr size_t OFF_HBUF = 1024;                               // [2][B][H] bf16 = 128 KB
constexpr size_t OFF_CMID = OFF_HBUF + 2ull * Bn * Hn * 2;
constexpr size_t OFF_Y1   = OFF_CMID + (size_t)Bn * Hn * 4;     // [T][B][H] bf16 = 32 MB
constexpr size_t OFF_XG   = OFF_Y1 + (size_t)Tn * Bn * Hn * 2;  // [T][G][B] bf16 = 128 MB

// -------- helpers --------
__device__ __forceinline__ u16 f2b(float f) {
  union { float f; unsigned u; } v; v.f = f;
  unsigned r = v.u + 0x7fffu + ((v.u >> 16) & 1u);
  return (u16)(r >> 16);
}
__device__ __forceinline__ float b2f(u16 u) {
  union { unsigned u; float f; } v; v.u = ((unsigned)u) << 16; return v.f;
}
__device__ __forceinline__ s16x8 pack8(float4 lo, float4 hi) {
  s16x8 r;
  r[0] = (short)f2b(lo.x); r[1] = (short)f2b(lo.y); r[2] = (short)f2b(lo.z); r[3] = (short)f2b(lo.w);
  r[4] = (short)f2b(hi.x); r[5] = (short)f2b(hi.y); r[6] = (short)f2b(hi.z); r[7] = (short)f2b(hi.w);
  return r;
}
__device__ __forceinline__ float sigm(float x) {
  float e = __builtin_amdgcn_exp2f(-1.4426950408889634f * x);
  return __builtin_amdgcn_rcpf(1.0f + e);
}
__device__ __forceinline__ float tanh_(float x) {
  float e = __builtin_amdgcn_exp2f(-2.885390081777927f * x);
  return __builtin_amdgcn_rcpf(1.0f + e) * 2.0f - 1.0f;
}
// agent-scope (device-coherent, cache-bypassing) relaxed atomics
__device__ __forceinline__ u64 ld64_sc(const u64* p) {
  return __hip_atomic_load(p, __ATOMIC_RELAXED, __HIP_MEMORY_SCOPE_AGENT);
}
__device__ __forceinline__ void st64_sc(u64* p, u64 v) {
  __hip_atomic_store(p, v, __ATOMIC_RELAXED, __HIP_MEMORY_SCOPE_AGENT);
}
__device__ __forceinline__ void st16_sc(u16* p, u16 v) {
  __hip_atomic_store(p, v, __ATOMIC_RELAXED, __HIP_MEMORY_SCOPE_AGENT);
}
__device__ __forceinline__ u32 ld32_sc(const u32* p) {
  return __hip_atomic_load(p, __ATOMIC_RELAXED, __HIP_MEMORY_SCOPE_AGENT);
}
__device__ __forceinline__ void st32_sc(u32* p, u32 v) {
  __hip_atomic_store(p, v, __ATOMIC_RELAXED, __HIP_MEMORY_SCOPE_AGENT);
}

// -------- projection GEMM: xg[t][n][b] = A[m][:] . W[n][:] + bih[n] + bhh[n] --------
// grid = (16 n-blocks, 256 m-blocks): consecutive bids share the A-tile -> L2/L3 hits.
template<bool AF32>
__global__ __launch_bounds__(256)
void proj_kernel(const void* __restrict__ Ap, const float* __restrict__ W,
                 const float* __restrict__ bih, const float* __restrict__ bhh,
                 u16* __restrict__ xg)
{
  const int lane = threadIdx.x & 63, wave = threadIdx.x >> 6;
  const int lrow = lane & 15, lk8 = (lane >> 4) << 3;
  const int m0 = blockIdx.y * 128 + (wave & 1) * 64;
  const int n0 = blockIdx.x * 128 + (wave >> 1) * 64;
  f32x4 acc[4][4] = {};
  for (int ks = 0; ks < 16; ++ks) {
    const int k0 = ks * 32 + lk8;
    s16x8 af[4], bfr[4];
#pragma unroll
    for (int mt = 0; mt < 4; ++mt) {
      const int row = m0 + mt * 16 + lrow;
      if constexpr (AF32) {
        const float* ap = (const float*)Ap + (size_t)row * Hn + k0;
        float4 lo = *(const float4*)ap, hi = *(const float4*)(ap + 4);
        af[mt] = pack8(lo, hi);
      } else {
        af[mt] = *(const s16x8*)((const u16*)Ap + (size_t)row * Hn + k0);
      }
    }
#pragma unroll
    for (int nt = 0; nt < 4; ++nt) {
      const float* wp = W + (size_t)(n0 + nt * 16 + lrow) * Hn + k0;
      float4 lo = *(const float4*)wp, hi = *(const float4*)(wp + 4);
      bfr[nt] = pack8(lo, hi);
    }
#pragma unroll
    for (int mt = 0; mt < 4; ++mt)
#pragma unroll
      for (int nt = 0; nt < 4; ++nt)
        acc[mt][nt] = __builtin_amdgcn_mfma_f32_16x16x32_bf16(af[mt], bfr[nt], acc[mt][nt], 0, 0, 0);
  }
  const int rbase = (lane >> 4) << 2;
#pragma unroll
  for (int nt = 0; nt < 4; ++nt) {
    const int n = n0 + nt * 16 + lrow;
    const float bias = bih[n] + bhh[n];
#pragma unroll
    for (int mt = 0; mt < 4; ++mt) {
      const int m = m0 + mt * 16 + rbase;
      const int t = m >> 6, b = m & 63;
      ushort4 v;
      v.x = f2b(acc[mt][nt][0] + bias);
      v.y = f2b(acc[mt][nt][1] + bias);
      v.z = f2b(acc[mt][nt][2] + bias);
      v.w = f2b(acc[mt][nt][3] + bias);
      *(ushort4*)(xg + ((size_t)t * Gn + n) * Bn + b) = v;
    }
  }
}

// -------- persistent LSTM scan: 4 batch-groups x 16 gate-slice WGs --------
// WG (g,s): batch rows g*16..+16, h-cols s*32..+32. Exchange only within group
// (flag-based, no RMW). Wave w: j0 = s*32 + w*8. Weights in registers.
__global__ __launch_bounds__(256, 1)
void scan_kernel(const u16* __restrict__ xg, const float* __restrict__ Whh,
                 const float* __restrict__ hinit, const float* __restrict__ cinit,
                 u16* __restrict__ hbuf, u16* __restrict__ y1,
                 float* __restrict__ c_fin, float* __restrict__ h_fin,
                 u32* __restrict__ flags, const int phase)
{
  const int g = blockIdx.x >> 4, s = blockIdx.x & (NS - 1);
  const int tid = threadIdx.x;
  const int lane = tid & 63, w = tid >> 6;
  const int x16 = lane & 15, grp = lane >> 4;
  const int jj = x16 & 7;                 // also the LDS swizzle key
  const int j0 = s * 32 + w * 8;
  const int brow = g * 16;
  const int bth = brow + grp * 4;

  __shared__ char hlds[16 * 1024];        // group's h: 16 rows x 64 chunks of 16B, XOR-swizzled

  u32* flg = flags + g * 32;              // this group's 16 flags (one 64B line)

  // loop-invariant weight fragments: wave holds 32 gate-rows x K=512 (128 VGPR)
  s16x8 bw[2][16];
#pragma unroll
  for (int nt = 0; nt < 2; ++nt) {
    const int q = nt * 2 + (x16 >> 3);                    // gate 0..3 (i,f,g,o)
    const size_t grow = (size_t)q * Hn + j0 + jj;         // W_hh row
#pragma unroll
    for (int ks = 0; ks < 16; ++ks) {
      const float* wp = Whh + grow * Hn + ks * 32 + grp * 8;
      float4 lo = *(const float4*)wp, hi = *(const float4*)(wp + 4);
      bw[nt][ks] = pack8(lo, hi);
    }
  }

  float c[4];
#pragma unroll
  for (int r = 0; r < 4; ++r) c[r] = cinit[(size_t)(bth + r) * Hn + j0 + jj];

  unsigned ep = 0;
  if (phase == 1) {  // publish h0 slice into parity 0, then flag=1
    if (tid < 128) {
      const int row = tid >> 3, cq = tid & 7;
      const float* hp = hinit + (size_t)(brow + row) * Hn + s * 32 + cq * 4;
      u64 v = (u64)f2b(hp[0]) | ((u64)f2b(hp[1]) << 16)
            | ((u64)f2b(hp[2]) << 32) | ((u64)f2b(hp[3]) << 48);
      st64_sc((u64*)(hbuf + (size_t)(brow + row) * Hn + s * 32 + cq * 4), v);
    }
    asm volatile("s_waitcnt vmcnt(0)" ::: "memory");
    __syncthreads();
    if (tid == 0) st32_sc(flg + s, 1u);
    ep = 1;
  }
  // phase 2: parity 0 already holds layer-1 final h (written by phase 1's last step);
  // ep=0 so the first wait passes immediately (flags zeroed by host memset).

  const size_t grow0 = (size_t)(0 * 2 + (x16 >> 3)) * Hn + j0 + jj;
  const size_t grow1 = (size_t)(1 * 2 + (x16 >> 3)) * Hn + j0 + jj;
  ushort4 xv0 = *(const ushort4*)(xg + grow0 * Bn + bth);
  ushort4 xv1 = *(const ushort4*)(xg + grow1 * Bn + bth);

  for (int t = 0; t < Tn; ++t) {
    // per-wave group wait: all 16 flags >= ep. Own-WG flag (set only after all
    // waves drained loads/stores/LDS at the end-of-step barrier) gates WAR safety.
    while (true) {
      u32 v = (lane < NS) ? ld32_sc(flg + lane) : 0xFFFFFFFFu;
      if (__all(v >= ep)) break;
      __builtin_amdgcn_s_sleep(1);
    }

    const u16* hprev = hbuf + (size_t)(t & 1) * Bn * Hn;
    u16* hnext = hbuf + (size_t)((t + 1) & 1) * Bn * Hn;

    // cooperative coherent load of group's h (16 rows x 1KB = 16KB)
    u64 hq0[4], hq1[4];
#pragma unroll
    for (int i = 0; i < 4; ++i) {
      const int idx = tid + i * 256;
      const int row = idx >> 6, ci = idx & 63;
      const u64* src = (const u64*)(hprev + (size_t)(brow + row) * Hn) + ci * 2;
      hq0[i] = ld64_sc(src);
      hq1[i] = ld64_sc(src + 1);
    }
    // prefetch next xg slice EARLY so HBM latency hides under this step
    ushort4 xn0, xn1;
    if (t + 1 < Tn) {
      xn0 = *(const ushort4*)(xg + ((size_t)(t + 1) * Gn + grow0) * Bn + bth);
      xn1 = *(const ushort4*)(xg + ((size_t)(t + 1) * Gn + grow1) * Bn + bth);
    }
    // stage into LDS with 16B-chunk XOR swizzle (conflict-free ds_read_b128)
#pragma unroll
    for (int i = 0; i < 4; ++i) {
      const int idx = tid + i * 256;
      const int row = idx >> 6, ci = idx & 63;
      u64x2 v; v[0] = hq0[i]; v[1] = hq1[i];
      *(u64x2*)(hlds + row * 1024 + ((ci ^ (row & 7)) * 16)) = v;
    }
    __syncthreads();

    f32x4 acc0, acc1;
    acc0[0] = b2f(xv0.x); acc0[1] = b2f(xv0.y); acc0[2] = b2f(xv0.z); acc0[3] = b2f(xv0.w);
    acc1[0] = b2f(xv1.x); acc1[1] = b2f(xv1.y); acc1[2] = b2f(xv1.z); acc1[3] = b2f(xv1.w);
#pragma unroll
    for (int ks = 0; ks < 16; ++ks) {
      s16x8 a = *(const s16x8*)(hlds + x16 * 1024 + ((((ks << 2) + grp) ^ jj) * 16));
      acc0 = __builtin_amdgcn_mfma_f32_16x16x32_bf16(a, bw[0][ks], acc0, 0, 0, 0);
      acc1 = __builtin_amdgcn_mfma_f32_16x16x32_bf16(a, bw[1][ks], acc1, 0, 0, 0);
    }
    // tile0 rows: i(j)/f(j); tile1: g(j)/o(j); pair via shfl_xor(8)
    float hv[4];
#pragma unroll
    for (int r = 0; r < 4; ++r) {
      const float p0 = acc0[r], p1 = acc1[r];
      const float q0 = __shfl_xor(p0, 8, 64);
      const float q1 = __shfl_xor(p1, 8, 64);
      const bool lo = (x16 < 8);
      const float gi = lo ? p0 : q0;
      const float gf = lo ? q0 : p0;
      const float gg = lo ? p1 : q1;
      const float go = lo ? q1 : p1;
      const float cn = sigm(gf) * c[r] + sigm(gi) * tanh_(gg);
      c[r] = cn;
      hv[r] = sigm(go) * tanh_(cn);
    }
    if (x16 < 8) {
#pragma unroll
      for (int r = 0; r < 4; ++r) {
        const int b = bth + r;
        const u16 hb = f2b(hv[r]);
        st16_sc(hnext + (size_t)b * Hn + j0 + jj, hb);   // 1KB/WG publish
        if (phase == 1) y1[((size_t)t * Bn + b) * Hn + j0 + jj] = hb;
        if (phase == 2 && t == Tn - 1) {
          h_fin[(size_t)b * Hn + j0 + jj] = hv[r];
          c_fin[(size_t)b * Hn + j0 + jj] = c[r];
        }
      }
    }
    if (t + 1 < Tn) { xv0 = xn0; xv1 = xn1; }
    ++ep;
    asm volatile("s_waitcnt vmcnt(0)" ::: "memory");  // publish (and loads) ack'd
    __syncthreads();                                   // ...by ALL waves of this WG
    if (tid == 0) st32_sc(flg + s, ep);
  }
  if (phase == 1 && x16 < 8) {
#pragma unroll
    for (int r = 0; r < 4; ++r) c_fin[(size_t)(bth + r) * Hn + j0 + jj] = c[r];
  }
}

// -------- output head: out[b][o] = h2[b][:] . Wout[o][:] + bout[o] --------
__global__ __launch_bounds__(128)
void out_kernel(const float* __restrict__ h2, const float* __restrict__ Wout,
                const float* __restrict__ bout, float* __restrict__ out)
{
  const int b = blockIdx.x, o = threadIdx.x;
  const float4* hp = (const float4*)(h2 + (size_t)b * Hn);
  const float4* wp = (const float4*)(Wout + (size_t)o * Hn);
  float acc = 0.f;
#pragma unroll 4
  for (int k = 0; k < Hn / 4; ++k) {
    float4 h4 = hp[k], w4 = wp[k];
    acc += h4.x * w4.x + h4.y * w4.y + h4.z * w4.z + h4.w * w4.w;
  }
  out[(size_t)b * On + o] = acc + bout[o];
}

extern "C" void kernel_launch(void* const* d_in, const int* in_sizes, int n_in,
                              void* d_out, int out_size, void* d_ws, size_t ws_size,
                              hipStream_t stream) {
  const float* x     = (const float*)d_in[0];
  const float* h0    = (const float*)d_in[1];
  const float* c0    = (const float*)d_in[2];
  const float* W_ih1 = (const float*)d_in[3];
  const float* W_hh1 = (const float*)d_in[4];
  const float* b_ih1 = (const float*)d_in[5];
  const float* b_hh1 = (const float*)d_in[6];
  const float* W_ih2 = (const float*)d_in[7];
  const float* W_hh2 = (const float*)d_in[8];
  const float* b_ih2 = (const float*)d_in[9];
  const float* b_hh2 = (const float*)d_in[10];
  const float* W_out = (const float*)d_in[11];
  const float* b_out = (const float*)d_in[12];

  float* out    = (float*)d_out;
  float* h2_out = out + (size_t)Bn * On;
  float* c2_out = h2_out + (size_t)Bn * Hn;

  char* w = (char*)d_ws;
  u32*   flg1  = (u32*)(w + OFF_BAR);
  u32*   flg2  = (u32*)(w + OFF_BAR + 512);
  u16*   hbuf  = (u16*)(w + OFF_HBUF);
  float* c_mid = (float*)(w + OFF_CMID);
  u16*   y1    = (u16*)(w + OFF_Y1);
  u16*   xg    = (u16*)(w + OFF_XG);

  hipMemsetAsync(w, 0, 1024, stream);  // zero both flag zones (replay-safe)

  dim3 pgrid(Gn / 128, (Tn * Bn) / 128);  // (16 n, 256 m): n-blocks adjacent
  proj_kernel<true ><<<pgrid, 256, 0, stream>>>(x,  W_ih1, b_ih1, b_hh1, xg);
  scan_kernel<<<NG * NS, 256, 0, stream>>>(xg, W_hh1, h0, c0, hbuf, y1, c_mid, nullptr, flg1, 1);
  proj_kernel<false><<<pgrid, 256, 0, stream>>>(y1, W_ih2, b_ih2, b_hh2, xg);
  scan_kernel<<<NG * NS, 256, 0, stream>>>(xg, W_hh2, nullptr, c_mid, hbuf, y1, c2_out, h2_out, flg2, 2);
  out_kernel<<<Bn, 128, 0, stream>>>(h2_out, W_out, b_out, out);
}

// Round 4
// 4080.084 us; speedup vs baseline: 1.9380x; 1.0676x over previous
//
#include <hip/hip_runtime.h>

typedef unsigned short u16;
typedef unsigned int u32;
typedef unsigned long long u64;
using f32x4 = __attribute__((ext_vector_type(4))) float;
using s16x8 = __attribute__((ext_vector_type(8))) short;
using u64x2 = __attribute__((ext_vector_type(2))) unsigned long long;

constexpr int Tn = 512, Bn = 64, Hn = 512, Gn = 2048, On = 128;
constexpr int NS = 16;  // gate-slice WGs per batch group (exchange set)
constexpr int NG = 4;   // batch groups (no cross-group communication)

// -------- workspace layout (bytes) --------
constexpr size_t OFF_BAR  = 0;                                  // 1024 B: scan1 flags, scan2 at +512
constexpr size_t OFF_HBUF = 1024;                               // [2][B][H] bf16 = 128 KB
constexpr size_t OFF_CMID = OFF_HBUF + 2ull * Bn * Hn * 2;
constexpr size_t OFF_Y1   = OFF_CMID + (size_t)Bn * Hn * 4;     // [T][B][H] bf16 = 32 MB (also x_bf during proj1)
constexpr size_t OFF_XG   = OFF_Y1 + (size_t)Tn * Bn * Hn * 2;  // [T][G][B] bf16 = 128 MB

// -------- helpers --------
__device__ __forceinline__ u16 f2b(float f) {
  union { float f; unsigned u; } v; v.f = f;
  unsigned r = v.u + 0x7fffu + ((v.u >> 16) & 1u);
  return (u16)(r >> 16);
}
__device__ __forceinline__ float b2f(u16 u) {
  union { unsigned u; float f; } v; v.u = ((unsigned)u) << 16; return v.f;
}
__device__ __forceinline__ s16x8 pack8(float4 lo, float4 hi) {
  s16x8 r;
  r[0] = (short)f2b(lo.x); r[1] = (short)f2b(lo.y); r[2] = (short)f2b(lo.z); r[3] = (short)f2b(lo.w);
  r[4] = (short)f2b(hi.x); r[5] = (short)f2b(hi.y); r[6] = (short)f2b(hi.z); r[7] = (short)f2b(hi.w);
  return r;
}
__device__ __forceinline__ float sigm(float x) {
  float e = __builtin_amdgcn_exp2f(-1.4426950408889634f * x);
  return __builtin_amdgcn_rcpf(1.0f + e);
}
__device__ __forceinline__ float tanh_(float x) {
  float e = __builtin_amdgcn_exp2f(-2.885390081777927f * x);
  return __builtin_amdgcn_rcpf(1.0f + e) * 2.0f - 1.0f;
}
// agent-scope (device-coherent, cache-bypassing) relaxed atomics
__device__ __forceinline__ u64 ld64_sc(const u64* p) {
  return __hip_atomic_load(p, __ATOMIC_RELAXED, __HIP_MEMORY_SCOPE_AGENT);
}
__device__ __forceinline__ void st64_sc(u64* p, u64 v) {
  __hip_atomic_store(p, v, __ATOMIC_RELAXED, __HIP_MEMORY_SCOPE_AGENT);
}
__device__ __forceinline__ u32 ld32_sc(const u32* p) {
  return __hip_atomic_load(p, __ATOMIC_RELAXED, __HIP_MEMORY_SCOPE_AGENT);
}
__device__ __forceinline__ void st32_sc(u32* p, u32 v) {
  __hip_atomic_store(p, v, __ATOMIC_RELAXED, __HIP_MEMORY_SCOPE_AGENT);
}

// -------- f32 -> bf16 bulk convert --------
__global__ __launch_bounds__(256)
void cvt_kernel(const float* __restrict__ in, u16* __restrict__ out, int n4) {
  const int i = blockIdx.x * 256 + threadIdx.x;
  if (i < n4) {
    float4 v = ((const float4*)in)[i];
    ushort4 o; o.x = f2b(v.x); o.y = f2b(v.y); o.z = f2b(v.z); o.w = f2b(v.w);
    ((ushort4*)out)[i] = o;
  }
}

// -------- projection GEMM: xg[t][n][b] = A[m][:] . W[n][:] + bih[n] + bhh[n] --------
// A: [32768][512] bf16. W: [2048][512] f32. grid = (16 n, 256 m) for A-tile L2/L3 reuse.
__global__ __launch_bounds__(256)
void proj_kernel(const u16* __restrict__ Ap, const float* __restrict__ W,
                 const float* __restrict__ bih, const float* __restrict__ bhh,
                 u16* __restrict__ xg)
{
  const int lane = threadIdx.x & 63, wave = threadIdx.x >> 6;
  const int lrow = lane & 15, lk8 = (lane >> 4) << 3;
  const int m0 = blockIdx.y * 128 + (wave & 1) * 64;
  const int n0 = blockIdx.x * 128 + (wave >> 1) * 64;
  f32x4 acc[4][4] = {};
  for (int ks = 0; ks < 16; ++ks) {
    const int k0 = ks * 32 + lk8;
    s16x8 af[4], bfr[4];
#pragma unroll
    for (int mt = 0; mt < 4; ++mt)
      af[mt] = *(const s16x8*)(Ap + (size_t)(m0 + mt * 16 + lrow) * Hn + k0);
#pragma unroll
    for (int nt = 0; nt < 4; ++nt) {
      const float* wp = W + (size_t)(n0 + nt * 16 + lrow) * Hn + k0;
      float4 lo = *(const float4*)wp, hi = *(const float4*)(wp + 4);
      bfr[nt] = pack8(lo, hi);
    }
#pragma unroll
    for (int mt = 0; mt < 4; ++mt)
#pragma unroll
      for (int nt = 0; nt < 4; ++nt)
        acc[mt][nt] = __builtin_amdgcn_mfma_f32_16x16x32_bf16(af[mt], bfr[nt], acc[mt][nt], 0, 0, 0);
  }
  const int rbase = (lane >> 4) << 2;
#pragma unroll
  for (int nt = 0; nt < 4; ++nt) {
    const int n = n0 + nt * 16 + lrow;
    const float bias = bih[n] + bhh[n];
#pragma unroll
    for (int mt = 0; mt < 4; ++mt) {
      const int m = m0 + mt * 16 + rbase;
      const int t = m >> 6, b = m & 63;
      ushort4 v;
      v.x = f2b(acc[mt][nt][0] + bias);
      v.y = f2b(acc[mt][nt][1] + bias);
      v.z = f2b(acc[mt][nt][2] + bias);
      v.w = f2b(acc[mt][nt][3] + bias);
      *(ushort4*)(xg + ((size_t)t * Gn + n) * Bn + b) = v;
    }
  }
}

// -------- persistent LSTM scan: 4 batch-groups x 16 gate-slice WGs --------
__global__ __launch_bounds__(256, 1)
void scan_kernel(const u16* __restrict__ xg, const float* __restrict__ Whh,
                 const float* __restrict__ hinit, const float* __restrict__ cinit,
                 u16* __restrict__ hbuf, u16* __restrict__ y1,
                 float* __restrict__ c_fin, float* __restrict__ h_fin,
                 u32* __restrict__ flags, const int phase)
{
  const int g = blockIdx.x >> 4, s = blockIdx.x & (NS - 1);
  const int tid = threadIdx.x;
  const int lane = tid & 63, w = tid >> 6;
  const int x16 = lane & 15, grp = lane >> 4;
  const int jj = x16 & 7;
  const int j0 = s * 32 + w * 8;
  const int brow = g * 16;
  const int bth = brow + grp * 4;

  __shared__ char hlds[16 * 1024];   // group h: 16 rows x 64 x 16B chunks, XOR-swizzled
  __shared__ u16 hstage[16][32];     // this WG's h-slice staging for coalesced publish

  u32* flg = flags + g * 32;

  // loop-invariant weight fragments (32 gate-rows x K=512 per wave, 128 VGPR)
  s16x8 bw[2][16];
#pragma unroll
  for (int nt = 0; nt < 2; ++nt) {
    const int q = nt * 2 + (x16 >> 3);                    // gate 0..3 (i,f,g,o)
    const size_t grow = (size_t)q * Hn + j0 + jj;
#pragma unroll
    for (int ks = 0; ks < 16; ++ks) {
      const float* wp = Whh + grow * Hn + ks * 32 + grp * 8;
      float4 lo = *(const float4*)wp, hi = *(const float4*)(wp + 4);
      bw[nt][ks] = pack8(lo, hi);
    }
  }

  float c[4];
#pragma unroll
  for (int r = 0; r < 4; ++r) c[r] = cinit[(size_t)(bth + r) * Hn + j0 + jj];

  unsigned ep = 0;
  if (phase == 1) {  // publish h0 slice into parity 0
    if (tid < 128) {
      const int row = tid >> 3, cq = tid & 7;
      const float* hp = hinit + (size_t)(brow + row) * Hn + s * 32 + cq * 4;
      u64 v = (u64)f2b(hp[0]) | ((u64)f2b(hp[1]) << 16)
            | ((u64)f2b(hp[2]) << 32) | ((u64)f2b(hp[3]) << 48);
      st64_sc((u64*)(hbuf + (size_t)(brow + row) * Hn + s * 32 + cq * 4), v);
    }
    asm volatile("s_waitcnt vmcnt(0)" ::: "memory");
    __syncthreads();
    if (tid == 0) st32_sc(flg + s, 1u);
    ep = 1;
  }
  // phase 2: parity 0 holds layer-1 final h; ep=0 passes the first wait.

  const size_t grow0 = (size_t)(0 * 2 + (x16 >> 3)) * Hn + j0 + jj;
  const size_t grow1 = (size_t)(1 * 2 + (x16 >> 3)) * Hn + j0 + jj;
  ushort4 xv0 = *(const ushort4*)(xg + grow0 * Bn + bth);
  ushort4 xv1 = *(const ushort4*)(xg + grow1 * Bn + bth);

  for (int t = 0; t < Tn; ++t) {
    while (true) {
      u32 v = (lane < NS) ? ld32_sc(flg + lane) : 0xFFFFFFFFu;
      if (__all(v >= ep)) break;
      __builtin_amdgcn_s_sleep(1);
    }

    const u16* hprev = hbuf + (size_t)(t & 1) * Bn * Hn;
    u16* hnext = hbuf + (size_t)((t + 1) & 1) * Bn * Hn;

    // cooperative coherent load of group's h (16 KB)
    u64 hq0[4], hq1[4];
#pragma unroll
    for (int i = 0; i < 4; ++i) {
      const int idx = tid + i * 256;
      const int row = idx >> 6, ci = idx & 63;
      const u64* src = (const u64*)(hprev + (size_t)(brow + row) * Hn) + ci * 2;
      hq0[i] = ld64_sc(src);
      hq1[i] = ld64_sc(src + 1);
    }
    // prefetch next xg slice early (HBM latency hides under this step)
    ushort4 xn0, xn1;
    if (t + 1 < Tn) {
      xn0 = *(const ushort4*)(xg + ((size_t)(t + 1) * Gn + grow0) * Bn + bth);
      xn1 = *(const ushort4*)(xg + ((size_t)(t + 1) * Gn + grow1) * Bn + bth);
    }
    // stage into LDS, 16B-chunk XOR swizzle
#pragma unroll
    for (int i = 0; i < 4; ++i) {
      const int idx = tid + i * 256;
      const int row = idx >> 6, ci = idx & 63;
      u64x2 v; v[0] = hq0[i]; v[1] = hq1[i];
      *(u64x2*)(hlds + row * 1024 + ((ci ^ (row & 7)) * 16)) = v;
    }
    __syncthreads();

    f32x4 acc0, acc1;
    acc0[0] = b2f(xv0.x); acc0[1] = b2f(xv0.y); acc0[2] = b2f(xv0.z); acc0[3] = b2f(xv0.w);
    acc1[0] = b2f(xv1.x); acc1[1] = b2f(xv1.y); acc1[2] = b2f(xv1.z); acc1[3] = b2f(xv1.w);
#pragma unroll
    for (int ks = 0; ks < 16; ++ks) {
      s16x8 a = *(const s16x8*)(hlds + x16 * 1024 + ((((ks << 2) + grp) ^ jj) * 16));
      acc0 = __builtin_amdgcn_mfma_f32_16x16x32_bf16(a, bw[0][ks], acc0, 0, 0, 0);
      acc1 = __builtin_amdgcn_mfma_f32_16x16x32_bf16(a, bw[1][ks], acc1, 0, 0, 0);
    }
    // tile0 rows: i(j)/f(j); tile1: g(j)/o(j); pair via shfl_xor(8)
    float hv[4];
#pragma unroll
    for (int r = 0; r < 4; ++r) {
      const float p0 = acc0[r], p1 = acc1[r];
      const float q0 = __shfl_xor(p0, 8, 64);
      const float q1 = __shfl_xor(p1, 8, 64);
      const bool lo = (x16 < 8);
      const float gi = lo ? p0 : q0;
      const float gf = lo ? q0 : p0;
      const float gg = lo ? p1 : q1;
      const float go = lo ? q1 : p1;
      const float cn = sigm(gf) * c[r] + sigm(gi) * tanh_(gg);
      c[r] = cn;
      hv[r] = sigm(go) * tanh_(cn);
    }
    if (x16 < 8) {
#pragma unroll
      for (int r = 0; r < 4; ++r) {
        hstage[grp * 4 + r][w * 8 + jj] = f2b(hv[r]);
        if (phase == 2 && t == Tn - 1) {
          h_fin[(size_t)(bth + r) * Hn + j0 + jj] = hv[r];
          c_fin[(size_t)(bth + r) * Hn + j0 + jj] = c[r];
        }
      }
    }
    if (t + 1 < Tn) { xv0 = xn0; xv1 = xn1; }
    __syncthreads();
    // coalesced publish: 128 threads x 8B agent-scope (one 64B segment per 8 lanes)
    u64 yv = 0;
    if (tid < 128) {
      const int row = tid >> 3, cq = tid & 7;
      yv = *(const u64*)&hstage[row][cq * 4];
      st64_sc((u64*)(hnext + (size_t)(brow + row) * Hn + s * 32 + cq * 4), yv);
    }
    ++ep;
    asm volatile("s_waitcnt vmcnt(0)" ::: "memory");  // publish ack'd at coherence point
    __syncthreads();                                   // ...by ALL waves of this WG
    if (tid == 0) st32_sc(flg + s, ep);
    // y1 write AFTER the flag: its drain overlaps the next step's poll/load phase
    if (phase == 1 && tid < 128) {
      const int row = tid >> 3, cq = tid & 7;
      *(u64*)(y1 + ((size_t)t * Bn + (brow + row)) * Hn + s * 32 + cq * 4) = yv;
    }
  }
  if (phase == 1 && x16 < 8) {
#pragma unroll
    for (int r = 0; r < 4; ++r) c_fin[(size_t)(bth + r) * Hn + j0 + jj] = c[r];
  }
}

// -------- output head --------
__global__ __launch_bounds__(128)
void out_kernel(const float* __restrict__ h2, const float* __restrict__ Wout,
                const float* __restrict__ bout, float* __restrict__ out)
{
  const int b = blockIdx.x, o = threadIdx.x;
  const float4* hp = (const float4*)(h2 + (size_t)b * Hn);
  const float4* wp = (const float4*)(Wout + (size_t)o * Hn);
  float acc = 0.f;
#pragma unroll 4
  for (int k = 0; k < Hn / 4; ++k) {
    float4 h4 = hp[k], w4 = wp[k];
    acc += h4.x * w4.x + h4.y * w4.y + h4.z * w4.z + h4.w * w4.w;
  }
  out[(size_t)b * On + o] = acc + bout[o];
}

extern "C" void kernel_launch(void* const* d_in, const int* in_sizes, int n_in,
                              void* d_out, int out_size, void* d_ws, size_t ws_size,
                              hipStream_t stream) {
  const float* x     = (const float*)d_in[0];
  const float* h0    = (const float*)d_in[1];
  const float* c0    = (const float*)d_in[2];
  const float* W_ih1 = (const float*)d_in[3];
  const float* W_hh1 = (const float*)d_in[4];
  const float* b_ih1 = (const float*)d_in[5];
  const float* b_hh1 = (const float*)d_in[6];
  const float* W_ih2 = (const float*)d_in[7];
  const float* W_hh2 = (const float*)d_in[8];
  const float* b_ih2 = (const float*)d_in[9];
  const float* b_hh2 = (const float*)d_in[10];
  const float* W_out = (const float*)d_in[11];
  const float* b_out = (const float*)d_in[12];

  float* out    = (float*)d_out;
  float* h2_out = out + (size_t)Bn * On;
  float* c2_out = h2_out + (size_t)Bn * Hn;

  char* w = (char*)d_ws;
  u32*   flg1  = (u32*)(w + OFF_BAR);
  u32*   flg2  = (u32*)(w + OFF_BAR + 512);
  u16*   hbuf  = (u16*)(w + OFF_HBUF);
  float* c_mid = (float*)(w + OFF_CMID);
  u16*   y1    = (u16*)(w + OFF_Y1);   // holds x_bf until scan1 overwrites it
  u16*   xg    = (u16*)(w + OFF_XG);

  hipMemsetAsync(w, 0, 1024, stream);  // zero flag zones (replay-safe)

  // x -> bf16 into the y1 slot (dead until scan1 writes y1)
  const int n4 = Tn * Bn * Hn / 4;
  cvt_kernel<<<(n4 + 255) / 256, 256, 0, stream>>>(x, y1, n4);

  dim3 pgrid(Gn / 128, (Tn * Bn) / 128);
  proj_kernel<<<pgrid, 256, 0, stream>>>(y1, W_ih1, b_ih1, b_hh1, xg);
  scan_kernel<<<NG * NS, 256, 0, stream>>>(xg, W_hh1, h0, c0, hbuf, y1, c_mid, nullptr, flg1, 1);
  proj_kernel<<<pgrid, 256, 0, stream>>>(y1, W_ih2, b_ih2, b_hh2, xg);
  scan_kernel<<<NG * NS, 256, 0, stream>>>(xg, W_hh2, nullptr, c_mid, hbuf, y1, c2_out, h2_out, flg2, 2);
  out_kernel<<<Bn, 128, 0, stream>>>(h2_out, W_out, b_out, out);
}

// Round 5
// 3279.442 us; speedup vs baseline: 2.4112x; 1.2441x over previous
//
#include <hip/hip_runtime.h>

typedef unsigned short u16;
typedef unsigned int u32;
typedef unsigned long long u64;
using f32x4 = __attribute__((ext_vector_type(4))) float;
using s16x8 = __attribute__((ext_vector_type(8))) short;
using u64x2 = __attribute__((ext_vector_type(2))) unsigned long long;

constexpr int Tn = 512, Bn = 64, Hn = 512, Gn = 2048, On = 128;
constexpr int NS = 16;  // gate-slice WGs per batch group
constexpr int NG = 4;   // batch groups (independent)

// -------- workspace layout (bytes) --------
constexpr size_t OFF_CMID = 0;                                   // [B][H] f32 = 128 KB
constexpr size_t OFF_HMID = OFF_CMID + (size_t)Bn * Hn * 4;      // [B][H] f32 = 128 KB
constexpr size_t OFF_HT   = OFF_HMID + (size_t)Bn * Hn * 4;      // [T+1][B][H] bf16 = 33.6 MB (trail = exchange + y1)
constexpr size_t OFF_XG   = OFF_HT + (size_t)(Tn + 1) * Bn * Hn * 2;  // [T][G][B] bf16 = 128 MB

// -------- helpers --------
__device__ __forceinline__ u16 f2b(float f) {
  union { float f; unsigned u; } v; v.f = f;
  unsigned r = v.u + 0x7fffu + ((v.u >> 16) & 1u);
  return (u16)(r >> 16);
}
__device__ __forceinline__ float b2f(u16 u) {
  union { unsigned u; float f; } v; v.u = ((unsigned)u) << 16; return v.f;
}
__device__ __forceinline__ s16x8 pack8(float4 lo, float4 hi) {
  s16x8 r;
  r[0] = (short)f2b(lo.x); r[1] = (short)f2b(lo.y); r[2] = (short)f2b(lo.z); r[3] = (short)f2b(lo.w);
  r[4] = (short)f2b(hi.x); r[5] = (short)f2b(hi.y); r[6] = (short)f2b(hi.z); r[7] = (short)f2b(hi.w);
  return r;
}
__device__ __forceinline__ float sigm(float x) {
  float e = __builtin_amdgcn_exp2f(-1.4426950408889634f * x);
  return __builtin_amdgcn_rcpf(1.0f + e);
}
__device__ __forceinline__ float tanh_(float x) {
  float e = __builtin_amdgcn_exp2f(-2.885390081777927f * x);
  return __builtin_amdgcn_rcpf(1.0f + e) * 2.0f - 1.0f;
}
// agent-scope (device-coherent) relaxed atomics
__device__ __forceinline__ u64 ld64_sc(const u64* p) {
  return __hip_atomic_load(p, __ATOMIC_RELAXED, __HIP_MEMORY_SCOPE_AGENT);
}
__device__ __forceinline__ void st64_sc(u64* p, u64 v) {
  __hip_atomic_store(p, v, __ATOMIC_RELAXED, __HIP_MEMORY_SCOPE_AGENT);
}

// -------- projection GEMM: xg[t][n][b] = A[m][:] . W[n][:] + bih[n] + bhh[n] --------
// A: [32768][512] (f32 or bf16). W: [2048][512] f32. grid = (16 n, 256 m) for A-tile reuse.
template<bool AF32>
__global__ __launch_bounds__(256)
void proj_kernel(const void* __restrict__ Ap, const float* __restrict__ W,
                 const float* __restrict__ bih, const float* __restrict__ bhh,
                 u16* __restrict__ xg)
{
  const int lane = threadIdx.x & 63, wave = threadIdx.x >> 6;
  const int lrow = lane & 15, lk8 = (lane >> 4) << 3;
  const int m0 = blockIdx.y * 128 + (wave & 1) * 64;
  const int n0 = blockIdx.x * 128 + (wave >> 1) * 64;
  f32x4 acc[4][4] = {};
  for (int ks = 0; ks < 16; ++ks) {
    const int k0 = ks * 32 + lk8;
    s16x8 af[4], bfr[4];
#pragma unroll
    for (int mt = 0; mt < 4; ++mt) {
      const int row = m0 + mt * 16 + lrow;
      if constexpr (AF32) {
        const float* ap = (const float*)Ap + (size_t)row * Hn + k0;
        float4 lo = *(const float4*)ap, hi = *(const float4*)(ap + 4);
        af[mt] = pack8(lo, hi);
      } else {
        af[mt] = *(const s16x8*)((const u16*)Ap + (size_t)row * Hn + k0);
      }
    }
#pragma unroll
    for (int nt = 0; nt < 4; ++nt) {
      const float* wp = W + (size_t)(n0 + nt * 16 + lrow) * Hn + k0;
      float4 lo = *(const float4*)wp, hi = *(const float4*)(wp + 4);
      bfr[nt] = pack8(lo, hi);
    }
#pragma unroll
    for (int mt = 0; mt < 4; ++mt)
#pragma unroll
      for (int nt = 0; nt < 4; ++nt)
        acc[mt][nt] = __builtin_amdgcn_mfma_f32_16x16x32_bf16(af[mt], bfr[nt], acc[mt][nt], 0, 0, 0);
  }
  const int rbase = (lane >> 4) << 2;
#pragma unroll
  for (int nt = 0; nt < 4; ++nt) {
    const int n = n0 + nt * 16 + lrow;
    const float bias = bih[n] + bhh[n];
#pragma unroll
    for (int mt = 0; mt < 4; ++mt) {
      const int m = m0 + mt * 16 + rbase;
      const int t = m >> 6, b = m & 63;
      ushort4 v;
      v.x = f2b(acc[mt][nt][0] + bias);
      v.y = f2b(acc[mt][nt][1] + bias);
      v.z = f2b(acc[mt][nt][2] + bias);
      v.w = f2b(acc[mt][nt][3] + bias);
      *(ushort4*)(xg + ((size_t)t * Gn + n) * Bn + b) = v;
    }
  }
}

// -------- persistent LSTM scan: self-flagging trail buffer (no flags, no drains) --------
// ht: [T+1][B][H] bf16, pre-poisoned 0xFF. Region t = h after step t-1; region 0 = h0.
// WG (g,s): batch rows g*16..+16, h-cols s*32..+32. Consumers poll data chunks directly.
__global__ __launch_bounds__(256, 1)
void scan_kernel(const u16* __restrict__ xg, const float* __restrict__ Whh,
                 const float* __restrict__ hinit, const float* __restrict__ cinit,
                 u16* __restrict__ ht, float* __restrict__ h_fin, float* __restrict__ c_fin)
{
  const int g = blockIdx.x >> 4, s = blockIdx.x & (NS - 1);
  const int tid = threadIdx.x;
  const int lane = tid & 63, w = tid >> 6;
  const int x16 = lane & 15, grp = lane >> 4;
  const int jj = x16 & 7;
  const int j0 = s * 32 + w * 8;
  const int brow = g * 16;
  const int bth = brow + grp * 4;

  __shared__ char hlds[16 * 1024];   // group h: 16 rows x 64 x 16B chunks, XOR-swizzled
  __shared__ u16 hstage[16][32];     // WG's h-slice staging for coalesced publish

  // loop-invariant weight fragments (32 gate-rows x K=512 per wave, 128 VGPR)
  s16x8 bw[2][16];
#pragma unroll
  for (int nt = 0; nt < 2; ++nt) {
    const int q = nt * 2 + (x16 >> 3);                    // gate 0..3 (i,f,g,o)
    const size_t grow = (size_t)q * Hn + j0 + jj;
#pragma unroll
    for (int ks = 0; ks < 16; ++ks) {
      const float* wp = Whh + grow * Hn + ks * 32 + grp * 8;
      float4 lo = *(const float4*)wp, hi = *(const float4*)(wp + 4);
      bw[nt][ks] = pack8(lo, hi);
    }
  }

  float c[4];
#pragma unroll
  for (int r = 0; r < 4; ++r) c[r] = cinit[(size_t)(bth + r) * Hn + j0 + jj];

  // publish region 0 slice from hinit (f32 -> bf16)
  if (tid < 128) {
    const int row = tid >> 3, cq = tid & 7;
    const float* hp = hinit + (size_t)(brow + row) * Hn + s * 32 + cq * 4;
    u64 v = (u64)f2b(hp[0]) | ((u64)f2b(hp[1]) << 16)
          | ((u64)f2b(hp[2]) << 32) | ((u64)f2b(hp[3]) << 48);
    st64_sc((u64*)(ht + (size_t)(brow + row) * Hn + s * 32 + cq * 4), v);
  }

  const size_t grow0 = (size_t)(0 * 2 + (x16 >> 3)) * Hn + j0 + jj;
  const size_t grow1 = (size_t)(1 * 2 + (x16 >> 3)) * Hn + j0 + jj;
  ushort4 xv0 = *(const ushort4*)(xg + grow0 * Bn + bth);
  ushort4 xv1 = *(const ushort4*)(xg + grow1 * Bn + bth);

  for (int t = 0; t < Tn; ++t) {
    const u16* rt = ht + (size_t)t * Bn * Hn;
    // prefetch next xg slice first (latency hides under poll+compute)
    ushort4 xn0, xn1;
    if (t + 1 < Tn) {
      xn0 = *(const ushort4*)(xg + ((size_t)(t + 1) * Gn + grow0) * Bn + bth);
      xn1 = *(const ushort4*)(xg + ((size_t)(t + 1) * Gn + grow1) * Bn + bth);
    }
    // poll this thread's 8 u64 chunks of the group's 16KB slice (poll load IS the data load)
    // thread -> pairs: row = (tid>>6) + 4i, u64 col = (tid&63)*2 (+1)
    const u64* p0 = (const u64*)(rt + (size_t)(brow + (tid >> 6)) * Hn) + ((tid & 63) << 1);
    u64 v[8];
#pragma unroll
    for (int i = 0; i < 4; ++i) {
      v[2 * i]     = ld64_sc(p0 + i * 512);
      v[2 * i + 1] = ld64_sc(p0 + i * 512 + 1);
    }
    while (true) {
      bool all = true;
#pragma unroll
      for (int i = 0; i < 8; ++i) all = all && (v[i] != ~0ull);
      if (all) break;
      __builtin_amdgcn_s_sleep(1);
#pragma unroll
      for (int i = 0; i < 4; ++i) {
        if (v[2 * i]     == ~0ull) v[2 * i]     = ld64_sc(p0 + i * 512);
        if (v[2 * i + 1] == ~0ull) v[2 * i + 1] = ld64_sc(p0 + i * 512 + 1);
      }
    }
    // stage into LDS (16B-chunk XOR swizzle); data already in registers from the poll
#pragma unroll
    for (int i = 0; i < 4; ++i) {
      const int row = (tid >> 6) + 4 * i, cw = tid & 63;
      u64x2 q; q[0] = v[2 * i]; q[1] = v[2 * i + 1];
      *(u64x2*)(hlds + row * 1024 + ((cw ^ (row & 7)) * 16)) = q;
    }
    __syncthreads();

    f32x4 acc0, acc1;
    acc0[0] = b2f(xv0.x); acc0[1] = b2f(xv0.y); acc0[2] = b2f(xv0.z); acc0[3] = b2f(xv0.w);
    acc1[0] = b2f(xv1.x); acc1[1] = b2f(xv1.y); acc1[2] = b2f(xv1.z); acc1[3] = b2f(xv1.w);
#pragma unroll
    for (int ks = 0; ks < 16; ++ks) {
      s16x8 a = *(const s16x8*)(hlds + x16 * 1024 + ((((ks << 2) + grp) ^ jj) * 16));
      acc0 = __builtin_amdgcn_mfma_f32_16x16x32_bf16(a, bw[0][ks], acc0, 0, 0, 0);
      acc1 = __builtin_amdgcn_mfma_f32_16x16x32_bf16(a, bw[1][ks], acc1, 0, 0, 0);
    }
    // tile0 rows: i(j)/f(j); tile1: g(j)/o(j); pair via shfl_xor(8)
    float hv[4];
#pragma unroll
    for (int r = 0; r < 4; ++r) {
      const float p0v = acc0[r], p1v = acc1[r];
      const float q0 = __shfl_xor(p0v, 8, 64);
      const float q1 = __shfl_xor(p1v, 8, 64);
      const bool lo = (x16 < 8);
      const float gi = lo ? p0v : q0;
      const float gf = lo ? q0 : p0v;
      const float gg = lo ? p1v : q1;
      const float go = lo ? q1 : p1v;
      const float cn = sigm(gf) * c[r] + sigm(gi) * tanh_(gg);
      c[r] = cn;
      hv[r] = sigm(go) * tanh_(cn);
    }
    if (x16 < 8) {
#pragma unroll
      for (int r = 0; r < 4; ++r) {
        hstage[grp * 4 + r][w * 8 + jj] = f2b(hv[r]);
        if (t == Tn - 1) {
          h_fin[(size_t)(bth + r) * Hn + j0 + jj] = hv[r];
          c_fin[(size_t)(bth + r) * Hn + j0 + jj] = c[r];
        }
      }
    }
    if (t + 1 < Tn) { xv0 = xn0; xv1 = xn1; }
    __syncthreads();
    // publish region t+1: even tids (publishers span ALL 4 waves -> poll success at t+1
    // proves every wave finished step t's LDS reads; no end-of-step barrier needed)
    if (!(tid & 1)) {
      const int q = tid >> 1, row = q >> 3, cq = q & 7;
      const u64 yv = *(const u64*)&hstage[row][cq * 4];
      st64_sc((u64*)(ht + (size_t)(t + 1) * Bn * Hn + (size_t)(brow + row) * Hn + s * 32 + cq * 4), yv);
    }
  }
}

// -------- output head --------
__global__ __launch_bounds__(128)
void out_kernel(const float* __restrict__ h2, const float* __restrict__ Wout,
                const float* __restrict__ bout, float* __restrict__ out)
{
  const int b = blockIdx.x, o = threadIdx.x;
  const float4* hp = (const float4*)(h2 + (size_t)b * Hn);
  const float4* wp = (const float4*)(Wout + (size_t)o * Hn);
  float acc = 0.f;
#pragma unroll 4
  for (int k = 0; k < Hn / 4; ++k) {
    float4 h4 = hp[k], w4 = wp[k];
    acc += h4.x * w4.x + h4.y * w4.y + h4.z * w4.z + h4.w * w4.w;
  }
  out[(size_t)b * On + o] = acc + bout[o];
}

extern "C" void kernel_launch(void* const* d_in, const int* in_sizes, int n_in,
                              void* d_out, int out_size, void* d_ws, size_t ws_size,
                              hipStream_t stream) {
  const float* x     = (const float*)d_in[0];
  const float* h0    = (const float*)d_in[1];
  const float* c0    = (const float*)d_in[2];
  const float* W_ih1 = (const float*)d_in[3];
  const float* W_hh1 = (const float*)d_in[4];
  const float* b_ih1 = (const float*)d_in[5];
  const float* b_hh1 = (const float*)d_in[6];
  const float* W_ih2 = (const float*)d_in[7];
  const float* W_hh2 = (const float*)d_in[8];
  const float* b_ih2 = (const float*)d_in[9];
  const float* b_hh2 = (const float*)d_in[10];
  const float* W_out = (const float*)d_in[11];
  const float* b_out = (const float*)d_in[12];

  float* out    = (float*)d_out;
  float* h2_out = out + (size_t)Bn * On;
  float* c2_out = h2_out + (size_t)Bn * Hn;

  char* w = (char*)d_ws;
  float* c_mid = (float*)(w + OFF_CMID);
  float* h_mid = (float*)(w + OFF_HMID);
  u16*   ht    = (u16*)(w + OFF_HT);
  u16*   xg    = (u16*)(w + OFF_XG);

  const size_t ht_bytes = (size_t)(Tn + 1) * Bn * Hn * 2;
  dim3 pgrid(Gn / 128, (Tn * Bn) / 128);

  // poison trail (0xFFFF bf16 = NaN sentinel, unreachable for h)
  hipMemsetAsync(ht, 0xFF, ht_bytes, stream);
  proj_kernel<true ><<<pgrid, 256, 0, stream>>>(x, W_ih1, b_ih1, b_hh1, xg);
  scan_kernel<<<NG * NS, 256, 0, stream>>>(xg, W_hh1, h0, c0, ht, h_mid, c_mid);
  // trail regions 1..T are exactly y1[0..T-1]
  proj_kernel<false><<<pgrid, 256, 0, stream>>>(ht + (size_t)Bn * Hn, W_ih2, b_ih2, b_hh2, xg);
  hipMemsetAsync(ht, 0xFF, ht_bytes, stream);   // re-poison for scan2
  scan_kernel<<<NG * NS, 256, 0, stream>>>(xg, W_hh2, h_mid, c_mid, ht, h2_out, c2_out);
  out_kernel<<<Bn, 128, 0, stream>>>(h2_out, W_out, b_out, out);
}